// Round 1
// baseline (97.898 us; speedup 1.0000x reference)
//
#include <hip/hip_runtime.h>
#include <math.h>

#define BB 4
#define SS 4096
#define HH 1024
#define NH 16
#define DK 64
#define NMODES 4
#define NSB 32              // s-chunks for DFT kernel
#define SCHUNK (SS/NSB)     // 128
#define NJB (HH/256)        // 4 j-blocks
#define TWO_PI 6.28318530717958647692f

// ---------------- Kernel A: partial 4-mode DFT of x over s ----------------
// P[(b*NSB+sb)*H + j][8] = sum over s-chunk of x[b,s,j] * (cos, -sin) per mode
__global__ __launch_bounds__(256) void kA_dft(const float* __restrict__ x,
                                              const int* __restrict__ index,
                                              float* __restrict__ P) {
    __shared__ float tab[SCHUNK * 8];
    int t = threadIdx.x;
    int bid = blockIdx.x;
    int sb = bid & (NSB - 1);
    int jb = (bid >> 5) & (NJB - 1);
    int b  = bid >> 7;

    int kk0 = index[0], kk1 = index[1], kk2 = index[2], kk3 = index[3];
    // fill trig table for this s-chunk: tab[sl*8 + m*2] = cos, +1 = sin
    for (int u = t; u < SCHUNK * NMODES; u += 256) {
        int sl = u >> 2, m = u & 3;
        int k = (m == 0) ? kk0 : (m == 1) ? kk1 : (m == 2) ? kk2 : kk3;
        int sv = sb * SCHUNK + sl;
        int r = (k * sv) & (SS - 1);          // exact phase mod S (S power of 2)
        float ang = (float)r * (TWO_PI / (float)SS);
        float sn, cs;
        sincosf(ang, &sn, &cs);
        tab[sl * 8 + m * 2]     = cs;
        tab[sl * 8 + m * 2 + 1] = sn;
    }
    __syncthreads();

    int j = jb * 256 + t;
    float acc[8] = {0.f,0.f,0.f,0.f,0.f,0.f,0.f,0.f};
    const float* xp = x + ((size_t)(b * SS + sb * SCHUNK)) * HH + j;
    for (int r = 0; r < SCHUNK; ++r) {
        float xv = xp[(size_t)r * HH];
        float4 t0 = *(const float4*)&tab[r * 8];
        float4 t1 = *(const float4*)&tab[r * 8 + 4];
        acc[0] += xv * t0.x;  acc[1] -= xv * t0.y;   // G = sum x*(cos - i sin)
        acc[2] += xv * t0.z;  acc[3] -= xv * t0.w;
        acc[4] += xv * t1.x;  acc[5] -= xv * t1.y;
        acc[6] += xv * t1.z;  acc[7] -= xv * t1.w;
    }
    float* pp = P + ((size_t)((b * NSB + sb) * HH + j)) * 8;
    *(float4*)pp       = make_float4(acc[0], acc[1], acc[2], acc[3]);
    *(float4*)(pp + 4) = make_float4(acc[4], acc[5], acc[6], acc[7]);
}

// ---------------- Kernel A2: deterministic reduction of partials ----------
__global__ __launch_bounds__(256) void kA2_reduce(const float* __restrict__ P,
                                                  float* __restrict__ G) {
    int g = blockIdx.x * 256 + threadIdx.x;   // < B*H*8 = 32768
    int q = g & 7;
    int j = (g >> 3) & (HH - 1);
    int b = g >> 13;
    float s = 0.f;
    for (int sb = 0; sb < NSB; ++sb)
        s += P[((size_t)((b * NSB + sb) * HH + j)) * 8 + q];
    G[g] = s;
}

// ---------------- Kernel B: xm[b,c,m] = Wq[c,:] . G[b,:,m] + bias ----------
__global__ __launch_bounds__(256) void kB_proj(const float* __restrict__ Wq,
                                               const float* __restrict__ bq,
                                               const int* __restrict__ index,
                                               const float* __restrict__ G,
                                               float* __restrict__ XM) {
    __shared__ float Gs[HH * 8];   // 32 KB
    int t = threadIdx.x;
    int cb = blockIdx.x & 15;
    int b  = blockIdx.x >> 4;
    for (int u = t; u < HH * 8; u += 256) Gs[u] = G[(size_t)b * HH * 8 + u];
    __syncthreads();

    int cl = t >> 2, jq = t & 3;
    int c = cb * 64 + cl;
    float acc[8] = {0.f,0.f,0.f,0.f,0.f,0.f,0.f,0.f};
    for (int j0 = jq * 4; j0 < HH; j0 += 16) {
        float4 wv = *(const float4*)&Wq[(size_t)c * HH + j0];
        const float* gp = &Gs[j0 * 8];
        #pragma unroll
        for (int q = 0; q < 8; ++q) acc[q] += wv.x * gp[q];
        #pragma unroll
        for (int q = 0; q < 8; ++q) acc[q] += wv.y * gp[8 + q];
        #pragma unroll
        for (int q = 0; q < 8; ++q) acc[q] += wv.z * gp[16 + q];
        #pragma unroll
        for (int q = 0; q < 8; ++q) acc[q] += wv.w * gp[24 + q];
    }
    #pragma unroll
    for (int q = 0; q < 8; ++q) {
        acc[q] += __shfl_xor(acc[q], 1);
        acc[q] += __shfl_xor(acc[q], 2);
    }
    if (jq == 0) {
        float bias = bq[c];
        #pragma unroll
        for (int m = 0; m < NMODES; ++m)
            if (index[m] == 0) acc[2 * m] += bias * (float)SS;  // sum_s e^0 = S
        float* o = XM + ((size_t)(b * HH + c)) * 8;
        *(float4*)o       = make_float4(acc[0], acc[1], acc[2], acc[3]);
        *(float4*)(o + 4) = make_float4(acc[4], acc[5], acc[6], acc[7]);
    }
}

// ---------------- Kernel C: per-head complex mode-mix + irfft coefficients -
// coef layout per (b, c_out): [a0, cr1, ci1, cr2, ci2, cr3, ci3, 0]
// where y(s) = a0 + sum_k cr_k*cos(2pi k s/S) + ci_k*sin(2pi k s/S)
__global__ __launch_bounds__(64) void kC_modes(const float* __restrict__ wr,
                                               const float* __restrict__ wi,
                                               const float* __restrict__ XM,
                                               float* __restrict__ CF) {
    __shared__ float xs[DK * 8];   // xm slice for (b,h)
    int o = threadIdx.x;           // 0..63
    int h = blockIdx.x & 15;
    int b = blockIdx.x >> 4;
    for (int u = o; u < DK * 8; u += 64)
        xs[u] = XM[((size_t)(b * HH + h * DK)) * 8 + u];
    __syncthreads();

    float re[4] = {0.f,0.f,0.f,0.f}, im[4] = {0.f,0.f,0.f,0.f};
    for (int i = 0; i < DK; ++i) {
        float4 wrv = *(const float4*)&wr[(((size_t)(h * DK + i)) * DK + o) * 4];
        float4 wiv = *(const float4*)&wi[(((size_t)(h * DK + i)) * DK + o) * 4];
        float xr, xi;
        xr = xs[i * 8 + 0]; xi = xs[i * 8 + 1];
        re[0] += xr * wrv.x - xi * wiv.x;  im[0] += xr * wiv.x + xi * wrv.x;
        xr = xs[i * 8 + 2]; xi = xs[i * 8 + 3];
        re[1] += xr * wrv.y - xi * wiv.y;  im[1] += xr * wiv.y + xi * wrv.y;
        xr = xs[i * 8 + 4]; xi = xs[i * 8 + 5];
        re[2] += xr * wrv.z - xi * wiv.z;  im[2] += xr * wiv.z + xi * wrv.z;
        xr = xs[i * 8 + 6]; xi = xs[i * 8 + 7];
        re[3] += xr * wrv.w - xi * wiv.w;  im[3] += xr * wiv.w + xi * wrv.w;
    }
    int co = o * NH + h;               // faithful permute(0,3,2,1) flatten
    const float inv = 1.0f / (float)SS;
    float* cp = CF + ((size_t)(b * HH + co)) * 8;
    cp[0] =  re[0] * inv;              // irfft ignores Im(c0) (pocketfft c2r)
    cp[1] =  2.0f * re[1] * inv;
    cp[2] = -2.0f * im[1] * inv;
    cp[3] =  2.0f * re[2] * inv;
    cp[4] = -2.0f * im[2] * inv;
    cp[5] =  2.0f * re[3] * inv;
    cp[6] = -2.0f * im[3] * inv;
    cp[7] =  0.0f;
}

// ---------------- Kernel D: low-rank irfft + residual + LayerNorm ---------
__global__ __launch_bounds__(256) void kD_out(const float* __restrict__ x,
                                              const float* __restrict__ CF,
                                              const float* __restrict__ gamma,
                                              const float* __restrict__ beta,
                                              float* __restrict__ out) {
    __shared__ float redS[4], redQ[4];
    int t  = threadIdx.x;
    int b  = blockIdx.x >> 8;
    int s0 = (blockIdx.x & 255) * 16;
    int c0 = t * 4;

    // per-thread channels are fixed: keep their coefficients in registers
    const float* cp = CF + (size_t)b * HH * 8 + (size_t)c0 * 8;
    float4 cfa[8];
    #pragma unroll
    for (int e = 0; e < 4; ++e) {
        cfa[2 * e]     = *(const float4*)(cp + e * 8);
        cfa[2 * e + 1] = *(const float4*)(cp + e * 8 + 4);
    }
    float4 g4 = *(const float4*)&gamma[c0];
    float4 b4 = *(const float4*)&beta[c0];

    for (int r = 0; r < 16; ++r) {
        int s = s0 + r;
        float ang = (float)s * (TWO_PI / (float)SS);
        float s1, c1;
        sincosf(ang, &s1, &c1);
        float c2 = c1 * c1 - s1 * s1, s2 = 2.f * s1 * c1;
        float c3 = c2 * c1 - s2 * s1, s3 = s2 * c1 + c2 * s1;

        float4 xv = *(const float4*)&x[((size_t)(b * SS + s)) * HH + c0];
        float y[4];
        #pragma unroll
        for (int e = 0; e < 4; ++e) {
            float xe = (e == 0) ? xv.x : (e == 1) ? xv.y : (e == 2) ? xv.z : xv.w;
            float4 A = cfa[2 * e], Bv = cfa[2 * e + 1];
            y[e] = xe + A.x + A.y * c1 + A.z * s1 + A.w * c2
                      + Bv.x * s2 + Bv.y * c3 + Bv.z * s3;
        }
        float sm = y[0] + y[1] + y[2] + y[3];
        float sq = y[0]*y[0] + y[1]*y[1] + y[2]*y[2] + y[3]*y[3];
        #pragma unroll
        for (int off = 1; off < 64; off <<= 1) {
            sm += __shfl_xor(sm, off);
            sq += __shfl_xor(sq, off);
        }
        int w = t >> 6, lane = t & 63;
        if (lane == 0) { redS[w] = sm; redQ[w] = sq; }
        __syncthreads();
        float tot  = redS[0] + redS[1] + redS[2] + redS[3];
        float totq = redQ[0] + redQ[1] + redQ[2] + redQ[3];
        float mean = tot * (1.0f / (float)HH);
        float var  = totq * (1.0f / (float)HH) - mean * mean;
        float rs = rsqrtf(var + 1e-5f);
        float4 o4;
        o4.x = (y[0] - mean) * rs * g4.x + b4.x;
        o4.y = (y[1] - mean) * rs * g4.y + b4.y;
        o4.z = (y[2] - mean) * rs * g4.z + b4.z;
        o4.w = (y[3] - mean) * rs * g4.w + b4.w;
        *(float4*)&out[((size_t)(b * SS + s)) * HH + c0] = o4;
        __syncthreads();   // protect redS/redQ before next row overwrites
    }
}

extern "C" void kernel_launch(void* const* d_in, const int* in_sizes, int n_in,
                              void* d_out, int out_size, void* d_ws, size_t ws_size,
                              hipStream_t stream) {
    const float* x     = (const float*)d_in[0];
    const float* Wq    = (const float*)d_in[1];
    const float* bq    = (const float*)d_in[2];
    const float* wr    = (const float*)d_in[3];
    const float* wi    = (const float*)d_in[4];
    const float* gamma = (const float*)d_in[5];
    const float* beta  = (const float*)d_in[6];
    const int*   index = (const int*)d_in[7];
    float* out = (float*)d_out;
    float* ws  = (float*)d_ws;

    const size_t nP     = (size_t)BB * NSB * HH * 8;   // 1,048,576 floats (4 MB)
    const size_t nSmall = (size_t)BB * HH * 8;         // 32,768 floats (128 KB)

    float *P, *G, *XM, *CF;
    if (ws_size >= (nP + 3 * nSmall) * sizeof(float)) {
        P  = ws;
        G  = P + nP;
        XM = G + nSmall;
        CF = XM + nSmall;
    } else {
        // fall back: P lives in d_out (consumed by kA2 before kD writes out)
        P  = out;
        G  = ws;
        XM = G + nSmall;
        CF = XM + nSmall;
    }

    hipLaunchKernelGGL(kA_dft,     dim3(BB * NJB * NSB), dim3(256), 0, stream, x, index, P);
    hipLaunchKernelGGL(kA2_reduce, dim3(BB * HH * 8 / 256), dim3(256), 0, stream, P, G);
    hipLaunchKernelGGL(kB_proj,    dim3(BB * 16), dim3(256), 0, stream, Wq, bq, index, G, XM);
    hipLaunchKernelGGL(kC_modes,   dim3(BB * NH), dim3(64), 0, stream, wr, wi, XM, CF);
    hipLaunchKernelGGL(kD_out,     dim3(BB * (SS / 16)), dim3(256), 0, stream, x, CF, gamma, beta, out);
}

// Round 2
// 71.976 us; speedup vs baseline: 1.3601x; 1.3601x over previous
//
#include <hip/hip_runtime.h>
#include <math.h>

#define BB 4
#define SS 4096
#define HH 1024
#define NH 16
#define DK 64
#define NMODES 4
#define NSB 32              // s-chunks for DFT kernel
#define SCHUNK (SS/NSB)     // 128
#define NJB (HH/256)        // 4 j-blocks
#define TWO_PI 6.28318530717958647692f

// ---------------- Kernel A: partial 4-mode DFT of x over s ----------------
// P[(b*NSB+sb)*H + j][8] = sum over s-chunk of x[b,s,j] * (cos, -sin) per mode
__global__ __launch_bounds__(256) void kA_dft(const float* __restrict__ x,
                                              const int* __restrict__ index,
                                              float* __restrict__ P) {
    __shared__ float tab[SCHUNK * 8];
    int t = threadIdx.x;
    int bid = blockIdx.x;
    int sb = bid & (NSB - 1);
    int jb = (bid >> 5) & (NJB - 1);
    int b  = bid >> 7;

    int kk0 = index[0], kk1 = index[1], kk2 = index[2], kk3 = index[3];
    // fill trig table for this s-chunk: tab[sl*8 + m*2] = cos, +1 = sin
    for (int u = t; u < SCHUNK * NMODES; u += 256) {
        int sl = u >> 2, m = u & 3;
        int k = (m == 0) ? kk0 : (m == 1) ? kk1 : (m == 2) ? kk2 : kk3;
        int sv = sb * SCHUNK + sl;
        int r = (k * sv) & (SS - 1);          // exact phase mod S (S power of 2)
        float ang = (float)r * (TWO_PI / (float)SS);
        float sn, cs;
        sincosf(ang, &sn, &cs);
        tab[sl * 8 + m * 2]     = cs;
        tab[sl * 8 + m * 2 + 1] = sn;
    }
    __syncthreads();

    int j = jb * 256 + t;
    float acc[8] = {0.f,0.f,0.f,0.f,0.f,0.f,0.f,0.f};
    const float* xp = x + ((size_t)(b * SS + sb * SCHUNK)) * HH + j;
    for (int r = 0; r < SCHUNK; ++r) {
        float xv = xp[(size_t)r * HH];
        float4 t0 = *(const float4*)&tab[r * 8];
        float4 t1 = *(const float4*)&tab[r * 8 + 4];
        acc[0] += xv * t0.x;  acc[1] -= xv * t0.y;   // G = sum x*(cos - i sin)
        acc[2] += xv * t0.z;  acc[3] -= xv * t0.w;
        acc[4] += xv * t1.x;  acc[5] -= xv * t1.y;
        acc[6] += xv * t1.z;  acc[7] -= xv * t1.w;
    }
    float* pp = P + ((size_t)((b * NSB + sb) * HH + j)) * 8;
    *(float4*)pp       = make_float4(acc[0], acc[1], acc[2], acc[3]);
    *(float4*)(pp + 4) = make_float4(acc[4], acc[5], acc[6], acc[7]);
}

// ---------------- Kernel A2: deterministic reduction of partials ----------
__global__ __launch_bounds__(256) void kA2_reduce(const float* __restrict__ P,
                                                  float* __restrict__ G) {
    int g = blockIdx.x * 256 + threadIdx.x;   // < B*H*8 = 32768
    int q = g & 7;
    int j = (g >> 3) & (HH - 1);
    int b = g >> 13;
    float s = 0.f;
    for (int sb = 0; sb < NSB; ++sb)
        s += P[((size_t)((b * NSB + sb) * HH + j)) * 8 + q];
    G[g] = s;
}

// ---------------- Kernel B: xm[b,c,m] = Wq[c,:] . G[b,:,m] + bias ----------
__global__ __launch_bounds__(256) void kB_proj(const float* __restrict__ Wq,
                                               const float* __restrict__ bq,
                                               const int* __restrict__ index,
                                               const float* __restrict__ G,
                                               float* __restrict__ XM) {
    __shared__ float Gs[HH * 8];   // 32 KB
    int t = threadIdx.x;
    int cb = blockIdx.x & 15;
    int b  = blockIdx.x >> 4;
    for (int u = t; u < HH * 8; u += 256) Gs[u] = G[(size_t)b * HH * 8 + u];
    __syncthreads();

    int cl = t >> 2, jq = t & 3;
    int c = cb * 64 + cl;
    float acc[8] = {0.f,0.f,0.f,0.f,0.f,0.f,0.f,0.f};
    for (int j0 = jq * 4; j0 < HH; j0 += 16) {
        float4 wv = *(const float4*)&Wq[(size_t)c * HH + j0];
        const float* gp = &Gs[j0 * 8];
        #pragma unroll
        for (int q = 0; q < 8; ++q) acc[q] += wv.x * gp[q];
        #pragma unroll
        for (int q = 0; q < 8; ++q) acc[q] += wv.y * gp[8 + q];
        #pragma unroll
        for (int q = 0; q < 8; ++q) acc[q] += wv.z * gp[16 + q];
        #pragma unroll
        for (int q = 0; q < 8; ++q) acc[q] += wv.w * gp[24 + q];
    }
    #pragma unroll
    for (int q = 0; q < 8; ++q) {
        acc[q] += __shfl_xor(acc[q], 1);
        acc[q] += __shfl_xor(acc[q], 2);
    }
    if (jq == 0) {
        float bias = bq[c];
        #pragma unroll
        for (int m = 0; m < NMODES; ++m)
            if (index[m] == 0) acc[2 * m] += bias * (float)SS;  // sum_s e^0 = S
        float* o = XM + ((size_t)(b * HH + c)) * 8;
        *(float4*)o       = make_float4(acc[0], acc[1], acc[2], acc[3]);
        *(float4*)(o + 4) = make_float4(acc[4], acc[5], acc[6], acc[7]);
    }
}

// ---------------- Kernel C: per-head complex mode-mix + irfft coefficients -
// coef layout per (b, c_out): [a0, cr1, ci1, cr2, ci2, cr3, ci3, 0]
// where y(s) = a0 + sum_k cr_k*cos(2pi k s/S) + ci_k*sin(2pi k s/S)
// 512 threads: o = t&63, iq = t>>6 covers 8 i-values; LDS reduce over iq.
#define KC_IQ 8
#define KC_II (DK / KC_IQ)   // 8
__global__ __launch_bounds__(512) void kC_modes(const float* __restrict__ wr,
                                                const float* __restrict__ wi,
                                                const float* __restrict__ XM,
                                                float* __restrict__ CF) {
    __shared__ float xs[DK * 8];             // 2 KB: xm slice for (b,h)
    __shared__ float red[KC_IQ][DK][9];      // padded to 9: conflict-free
    int t = threadIdx.x;
    int o = t & 63, iq = t >> 6;
    int h = blockIdx.x & 15;
    int b = blockIdx.x >> 4;
    for (int u = t; u < DK * 8; u += 512)
        xs[u] = XM[((size_t)(b * HH + h * DK)) * 8 + u];
    __syncthreads();

    float re[4] = {0.f,0.f,0.f,0.f}, im[4] = {0.f,0.f,0.f,0.f};
    #pragma unroll
    for (int ii = 0; ii < KC_II; ++ii) {
        int i = iq * KC_II + ii;
        float4 wrv = *(const float4*)&wr[(((size_t)(h * DK + i)) * DK + o) * 4];
        float4 wiv = *(const float4*)&wi[(((size_t)(h * DK + i)) * DK + o) * 4];
        float xr, xi;
        xr = xs[i * 8 + 0]; xi = xs[i * 8 + 1];
        re[0] += xr * wrv.x - xi * wiv.x;  im[0] += xr * wiv.x + xi * wrv.x;
        xr = xs[i * 8 + 2]; xi = xs[i * 8 + 3];
        re[1] += xr * wrv.y - xi * wiv.y;  im[1] += xr * wiv.y + xi * wrv.y;
        xr = xs[i * 8 + 4]; xi = xs[i * 8 + 5];
        re[2] += xr * wrv.z - xi * wiv.z;  im[2] += xr * wiv.z + xi * wrv.z;
        xr = xs[i * 8 + 6]; xi = xs[i * 8 + 7];
        re[3] += xr * wrv.w - xi * wiv.w;  im[3] += xr * wiv.w + xi * wrv.w;
    }
    #pragma unroll
    for (int m = 0; m < 4; ++m) {
        red[iq][o][2 * m]     = re[m];
        red[iq][o][2 * m + 1] = im[m];
    }
    __syncthreads();
    if (iq == 0) {
        float rr[8];
        #pragma unroll
        for (int q = 0; q < 8; ++q) {
            float s = 0.f;
            #pragma unroll
            for (int g = 0; g < KC_IQ; ++g) s += red[g][o][q];
            rr[q] = s;
        }
        int co = o * NH + h;               // faithful permute(0,3,2,1) flatten
        const float inv = 1.0f / (float)SS;
        float* cp = CF + ((size_t)(b * HH + co)) * 8;
        cp[0] =  rr[0] * inv;              // irfft ignores Im(c0) (pocketfft c2r)
        cp[1] =  2.0f * rr[2] * inv;
        cp[2] = -2.0f * rr[3] * inv;
        cp[3] =  2.0f * rr[4] * inv;
        cp[4] = -2.0f * rr[5] * inv;
        cp[5] =  2.0f * rr[6] * inv;
        cp[6] = -2.0f * rr[7] * inv;
        cp[7] =  0.0f;
    }
}

// ---------------- Kernel D: low-rank irfft + residual + LayerNorm ---------
__global__ __launch_bounds__(256) void kD_out(const float* __restrict__ x,
                                              const float* __restrict__ CF,
                                              const float* __restrict__ gamma,
                                              const float* __restrict__ beta,
                                              float* __restrict__ out) {
    __shared__ float redS[4], redQ[4];
    int t  = threadIdx.x;
    int b  = blockIdx.x >> 8;
    int s0 = (blockIdx.x & 255) * 16;
    int c0 = t * 4;

    // per-thread channels are fixed: keep their coefficients in registers
    const float* cp = CF + (size_t)b * HH * 8 + (size_t)c0 * 8;
    float4 cfa[8];
    #pragma unroll
    for (int e = 0; e < 4; ++e) {
        cfa[2 * e]     = *(const float4*)(cp + e * 8);
        cfa[2 * e + 1] = *(const float4*)(cp + e * 8 + 4);
    }
    float4 g4 = *(const float4*)&gamma[c0];
    float4 b4 = *(const float4*)&beta[c0];

    for (int r = 0; r < 16; ++r) {
        int s = s0 + r;
        float ang = (float)s * (TWO_PI / (float)SS);
        float s1, c1;
        sincosf(ang, &s1, &c1);
        float c2 = c1 * c1 - s1 * s1, s2 = 2.f * s1 * c1;
        float c3 = c2 * c1 - s2 * s1, s3 = s2 * c1 + c2 * s1;

        float4 xv = *(const float4*)&x[((size_t)(b * SS + s)) * HH + c0];
        float y[4];
        #pragma unroll
        for (int e = 0; e < 4; ++e) {
            float xe = (e == 0) ? xv.x : (e == 1) ? xv.y : (e == 2) ? xv.z : xv.w;
            float4 A = cfa[2 * e], Bv = cfa[2 * e + 1];
            y[e] = xe + A.x + A.y * c1 + A.z * s1 + A.w * c2
                      + Bv.x * s2 + Bv.y * c3 + Bv.z * s3;
        }
        float sm = y[0] + y[1] + y[2] + y[3];
        float sq = y[0]*y[0] + y[1]*y[1] + y[2]*y[2] + y[3]*y[3];
        #pragma unroll
        for (int off = 1; off < 64; off <<= 1) {
            sm += __shfl_xor(sm, off);
            sq += __shfl_xor(sq, off);
        }
        int w = t >> 6, lane = t & 63;
        if (lane == 0) { redS[w] = sm; redQ[w] = sq; }
        __syncthreads();
        float tot  = redS[0] + redS[1] + redS[2] + redS[3];
        float totq = redQ[0] + redQ[1] + redQ[2] + redQ[3];
        float mean = tot * (1.0f / (float)HH);
        float var  = totq * (1.0f / (float)HH) - mean * mean;
        float rs = rsqrtf(var + 1e-5f);
        float4 o4;
        o4.x = (y[0] - mean) * rs * g4.x + b4.x;
        o4.y = (y[1] - mean) * rs * g4.y + b4.y;
        o4.z = (y[2] - mean) * rs * g4.z + b4.z;
        o4.w = (y[3] - mean) * rs * g4.w + b4.w;
        *(float4*)&out[((size_t)(b * SS + s)) * HH + c0] = o4;
        __syncthreads();   // protect redS/redQ before next row overwrites
    }
}

extern "C" void kernel_launch(void* const* d_in, const int* in_sizes, int n_in,
                              void* d_out, int out_size, void* d_ws, size_t ws_size,
                              hipStream_t stream) {
    const float* x     = (const float*)d_in[0];
    const float* Wq    = (const float*)d_in[1];
    const float* bq    = (const float*)d_in[2];
    const float* wr    = (const float*)d_in[3];
    const float* wi    = (const float*)d_in[4];
    const float* gamma = (const float*)d_in[5];
    const float* beta  = (const float*)d_in[6];
    const int*   index = (const int*)d_in[7];
    float* out = (float*)d_out;
    float* ws  = (float*)d_ws;

    const size_t nP     = (size_t)BB * NSB * HH * 8;   // 1,048,576 floats (4 MB)
    const size_t nSmall = (size_t)BB * HH * 8;         // 32,768 floats (128 KB)

    float *P, *G, *XM, *CF;
    if (ws_size >= (nP + 3 * nSmall) * sizeof(float)) {
        P  = ws;
        G  = P + nP;
        XM = G + nSmall;
        CF = XM + nSmall;
    } else {
        // fall back: P lives in d_out (consumed by kA2 before kD writes out)
        P  = out;
        G  = ws;
        XM = G + nSmall;
        CF = XM + nSmall;
    }

    hipLaunchKernelGGL(kA_dft,     dim3(BB * NJB * NSB), dim3(256), 0, stream, x, index, P);
    hipLaunchKernelGGL(kA2_reduce, dim3(BB * HH * 8 / 256), dim3(256), 0, stream, P, G);
    hipLaunchKernelGGL(kB_proj,    dim3(BB * 16), dim3(256), 0, stream, Wq, bq, index, G, XM);
    hipLaunchKernelGGL(kC_modes,   dim3(BB * NH), dim3(64), 0, stream, wr, wi, XM, CF);
    hipLaunchKernelGGL(kD_out,     dim3(BB * (SS / 16)), dim3(256), 0, stream, x, CF, gamma, beta, out);
}

// Round 3
// 68.325 us; speedup vs baseline: 1.4328x; 1.0534x over previous
//
#include <hip/hip_runtime.h>
#include <math.h>

#define BB 4
#define SS 4096
#define HH 1024
#define NH 16
#define DK 64
#define NMODES 4
#define NSB 64              // s-chunks for DFT kernel
#define SCHUNK (SS/NSB)     // 64
#define PPLANE ((size_t)BB * NSB * HH)   // one q-plane of P: 256K floats
#define TWO_PI 6.28318530717958647692f

// ---------------- Kernel A: partial 4-mode DFT of x over s ----------------
// Thread owns 4 consecutive channels (float4 loads). P stored as 8 planes:
// P[q*PPLANE + (b*NSB+sb)*HH + c] so each store is wave-contiguous.
__global__ __launch_bounds__(256) void kA_dft(const float* __restrict__ x,
                                              const int* __restrict__ index,
                                              float* __restrict__ P) {
    __shared__ float tab[SCHUNK * 8];
    int t  = threadIdx.x;
    int sb = blockIdx.x & (NSB - 1);
    int b  = blockIdx.x >> 6;

    // fill trig table: 64 rows x 4 modes = 256 entries, one per thread
    {
        int sl = t >> 2, m = t & 3;
        int k  = index[m];
        int sv = sb * SCHUNK + sl;
        int r  = (k * sv) & (SS - 1);          // exact phase mod S
        float ang = (float)r * (TWO_PI / (float)SS);
        float sn, cs;
        sincosf(ang, &sn, &cs);
        tab[sl * 8 + m * 2]     = cs;
        tab[sl * 8 + m * 2 + 1] = sn;
    }
    __syncthreads();

    int c0 = t * 4;
    float acc[4][8];
    #pragma unroll
    for (int e = 0; e < 4; ++e)
        #pragma unroll
        for (int q = 0; q < 8; ++q) acc[e][q] = 0.f;

    const float* xp = x + ((size_t)(b * SS + sb * SCHUNK)) * HH + c0;
    #pragma unroll 4
    for (int r = 0; r < SCHUNK; ++r) {
        float4 xv = *(const float4*)(xp + (size_t)r * HH);
        float4 t0 = *(const float4*)&tab[r * 8];      // broadcast (uniform addr)
        float4 t1 = *(const float4*)&tab[r * 8 + 4];
        float xe;
        #pragma unroll
        for (int e = 0; e < 4; ++e) {
            xe = (e == 0) ? xv.x : (e == 1) ? xv.y : (e == 2) ? xv.z : xv.w;
            acc[e][0] += xe * t0.x;  acc[e][1] -= xe * t0.y;  // G = sum x*(cos - i sin)
            acc[e][2] += xe * t0.z;  acc[e][3] -= xe * t0.w;
            acc[e][4] += xe * t1.x;  acc[e][5] -= xe * t1.y;
            acc[e][6] += xe * t1.z;  acc[e][7] -= xe * t1.w;
        }
    }
    size_t base = (size_t)(b * NSB + sb) * HH + c0;
    #pragma unroll
    for (int q = 0; q < 8; ++q) {
        *(float4*)&P[q * PPLANE + base] =
            make_float4(acc[0][q], acc[1][q], acc[2][q], acc[3][q]);
    }
}

// ---------------- Kernel A2: deterministic reduction of partials ----------
// output G[b][j][8]; thread g' = b*8192 + q*1024 + j (j fastest -> coalesced reads)
__global__ __launch_bounds__(256) void kA2_reduce(const float* __restrict__ P,
                                                  float* __restrict__ G) {
    int g = blockIdx.x * 256 + threadIdx.x;   // < B*8*H = 32768
    int j = g & (HH - 1);
    int q = (g >> 10) & 7;
    int b = g >> 13;
    float s = 0.f;
    for (int sb = 0; sb < NSB; ++sb)
        s += P[q * PPLANE + (size_t)(b * NSB + sb) * HH + j];
    G[((size_t)(b * HH + j)) * 8 + q] = s;
}

// ---------------- Kernel B: xm[b,c,m] = Wq[c,:] . G[b,:,m] + bias ----------
__global__ __launch_bounds__(256) void kB_proj(const float* __restrict__ Wq,
                                               const float* __restrict__ bq,
                                               const int* __restrict__ index,
                                               const float* __restrict__ G,
                                               float* __restrict__ XM) {
    __shared__ float Gs[HH * 8];   // 32 KB
    int t = threadIdx.x;
    int cb = blockIdx.x & 15;
    int b  = blockIdx.x >> 4;
    for (int u = t; u < HH * 8; u += 256) Gs[u] = G[(size_t)b * HH * 8 + u];
    __syncthreads();

    int cl = t >> 2, jq = t & 3;
    int c = cb * 64 + cl;
    float acc[8] = {0.f,0.f,0.f,0.f,0.f,0.f,0.f,0.f};
    for (int j0 = jq * 4; j0 < HH; j0 += 16) {
        float4 wv = *(const float4*)&Wq[(size_t)c * HH + j0];
        const float* gp = &Gs[j0 * 8];
        #pragma unroll
        for (int q = 0; q < 8; ++q) acc[q] += wv.x * gp[q];
        #pragma unroll
        for (int q = 0; q < 8; ++q) acc[q] += wv.y * gp[8 + q];
        #pragma unroll
        for (int q = 0; q < 8; ++q) acc[q] += wv.z * gp[16 + q];
        #pragma unroll
        for (int q = 0; q < 8; ++q) acc[q] += wv.w * gp[24 + q];
    }
    #pragma unroll
    for (int q = 0; q < 8; ++q) {
        acc[q] += __shfl_xor(acc[q], 1);
        acc[q] += __shfl_xor(acc[q], 2);
    }
    if (jq == 0) {
        float bias = bq[c];
        #pragma unroll
        for (int m = 0; m < NMODES; ++m)
            if (index[m] == 0) acc[2 * m] += bias * (float)SS;  // sum_s e^0 = S
        float* o = XM + ((size_t)(b * HH + c)) * 8;
        *(float4*)o       = make_float4(acc[0], acc[1], acc[2], acc[3]);
        *(float4*)(o + 4) = make_float4(acc[4], acc[5], acc[6], acc[7]);
    }
}

// ---------------- Kernel C: per-head complex mode-mix + irfft coefficients -
#define KC_IQ 8
#define KC_II (DK / KC_IQ)   // 8
__global__ __launch_bounds__(512) void kC_modes(const float* __restrict__ wr,
                                                const float* __restrict__ wi,
                                                const float* __restrict__ XM,
                                                float* __restrict__ CF) {
    __shared__ float xs[DK * 8];             // 2 KB: xm slice for (b,h)
    __shared__ float red[KC_IQ][DK][9];      // padded to 9: conflict-free
    int t = threadIdx.x;
    int o = t & 63, iq = t >> 6;
    int h = blockIdx.x & 15;
    int b = blockIdx.x >> 4;
    for (int u = t; u < DK * 8; u += 512)
        xs[u] = XM[((size_t)(b * HH + h * DK)) * 8 + u];
    __syncthreads();

    float re[4] = {0.f,0.f,0.f,0.f}, im[4] = {0.f,0.f,0.f,0.f};
    #pragma unroll
    for (int ii = 0; ii < KC_II; ++ii) {
        int i = iq * KC_II + ii;
        float4 wrv = *(const float4*)&wr[(((size_t)(h * DK + i)) * DK + o) * 4];
        float4 wiv = *(const float4*)&wi[(((size_t)(h * DK + i)) * DK + o) * 4];
        float xr, xi;
        xr = xs[i * 8 + 0]; xi = xs[i * 8 + 1];
        re[0] += xr * wrv.x - xi * wiv.x;  im[0] += xr * wiv.x + xi * wrv.x;
        xr = xs[i * 8 + 2]; xi = xs[i * 8 + 3];
        re[1] += xr * wrv.y - xi * wiv.y;  im[1] += xr * wiv.y + xi * wrv.y;
        xr = xs[i * 8 + 4]; xi = xs[i * 8 + 5];
        re[2] += xr * wrv.z - xi * wiv.z;  im[2] += xr * wiv.z + xi * wrv.z;
        xr = xs[i * 8 + 6]; xi = xs[i * 8 + 7];
        re[3] += xr * wrv.w - xi * wiv.w;  im[3] += xr * wiv.w + xi * wrv.w;
    }
    #pragma unroll
    for (int m = 0; m < 4; ++m) {
        red[iq][o][2 * m]     = re[m];
        red[iq][o][2 * m + 1] = im[m];
    }
    __syncthreads();
    if (iq == 0) {
        float rr[8];
        #pragma unroll
        for (int q = 0; q < 8; ++q) {
            float s = 0.f;
            #pragma unroll
            for (int g = 0; g < KC_IQ; ++g) s += red[g][o][q];
            rr[q] = s;
        }
        int co = o * NH + h;               // faithful permute(0,3,2,1) flatten
        const float inv = 1.0f / (float)SS;
        float* cp = CF + ((size_t)(b * HH + co)) * 8;
        cp[0] =  rr[0] * inv;              // irfft ignores Im(c0) (pocketfft c2r)
        cp[1] =  2.0f * rr[2] * inv;
        cp[2] = -2.0f * rr[3] * inv;
        cp[3] =  2.0f * rr[4] * inv;
        cp[4] = -2.0f * rr[5] * inv;
        cp[5] =  2.0f * rr[6] * inv;
        cp[6] = -2.0f * rr[7] * inv;
        cp[7] =  0.0f;
    }
}

// ---------------- Kernel D: low-rank irfft + residual + LayerNorm ---------
// 16 rows/block in two 8-row batches; batched shfl reduce, 4 syncs total.
#define KD_ROWS 16
#define KD_RB 8
__global__ __launch_bounds__(256) void kD_out(const float* __restrict__ x,
                                              const float* __restrict__ CF,
                                              const float* __restrict__ gamma,
                                              const float* __restrict__ beta,
                                              float* __restrict__ out) {
    __shared__ float red[4][KD_RB][2];
    int t  = threadIdx.x;
    int b  = blockIdx.x >> 8;
    int s0 = (blockIdx.x & 255) * KD_ROWS;
    int c0 = t * 4;

    const float* cp = CF + (size_t)b * HH * 8 + (size_t)c0 * 8;
    float4 cfa[8];
    #pragma unroll
    for (int e = 0; e < 4; ++e) {
        cfa[2 * e]     = *(const float4*)(cp + e * 8);
        cfa[2 * e + 1] = *(const float4*)(cp + e * 8 + 4);
    }
    float4 g4 = *(const float4*)&gamma[c0];
    float4 b4 = *(const float4*)&beta[c0];
    int w = t >> 6, lane = t & 63;

    for (int batch = 0; batch < KD_ROWS / KD_RB; ++batch) {
        float y[KD_RB][4], sm[KD_RB], sq[KD_RB];
        #pragma unroll
        for (int r = 0; r < KD_RB; ++r) {
            int s = s0 + batch * KD_RB + r;
            float ang = (float)s * (TWO_PI / (float)SS);
            float s1, c1;
            sincosf(ang, &s1, &c1);
            float c2 = c1 * c1 - s1 * s1, s2 = 2.f * s1 * c1;
            float c3 = c2 * c1 - s2 * s1, s3 = s2 * c1 + c2 * s1;

            float4 xv = *(const float4*)&x[((size_t)(b * SS + s)) * HH + c0];
            #pragma unroll
            for (int e = 0; e < 4; ++e) {
                float xe = (e == 0) ? xv.x : (e == 1) ? xv.y : (e == 2) ? xv.z : xv.w;
                float4 A = cfa[2 * e], Bv = cfa[2 * e + 1];
                y[r][e] = xe + A.x + A.y * c1 + A.z * s1 + A.w * c2
                             + Bv.x * s2 + Bv.y * c3 + Bv.z * s3;
            }
            sm[r] = y[r][0] + y[r][1] + y[r][2] + y[r][3];
            sq[r] = y[r][0]*y[r][0] + y[r][1]*y[r][1]
                  + y[r][2]*y[r][2] + y[r][3]*y[r][3];
        }
        #pragma unroll
        for (int off = 1; off < 64; off <<= 1) {
            #pragma unroll
            for (int r = 0; r < KD_RB; ++r) {
                sm[r] += __shfl_xor(sm[r], off);
                sq[r] += __shfl_xor(sq[r], off);
            }
        }
        if (lane == 0) {
            #pragma unroll
            for (int r = 0; r < KD_RB; ++r) {
                red[w][r][0] = sm[r];
                red[w][r][1] = sq[r];
            }
        }
        __syncthreads();
        #pragma unroll
        for (int r = 0; r < KD_RB; ++r) {
            int s = s0 + batch * KD_RB + r;
            float tot  = red[0][r][0] + red[1][r][0] + red[2][r][0] + red[3][r][0];
            float totq = red[0][r][1] + red[1][r][1] + red[2][r][1] + red[3][r][1];
            float mean = tot * (1.0f / (float)HH);
            float var  = totq * (1.0f / (float)HH) - mean * mean;
            float rs = rsqrtf(var + 1e-5f);
            float4 o4;
            o4.x = (y[r][0] - mean) * rs * g4.x + b4.x;
            o4.y = (y[r][1] - mean) * rs * g4.y + b4.y;
            o4.z = (y[r][2] - mean) * rs * g4.z + b4.z;
            o4.w = (y[r][3] - mean) * rs * g4.w + b4.w;
            *(float4*)&out[((size_t)(b * SS + s)) * HH + c0] = o4;
        }
        __syncthreads();   // protect red before next batch overwrites
    }
}

extern "C" void kernel_launch(void* const* d_in, const int* in_sizes, int n_in,
                              void* d_out, int out_size, void* d_ws, size_t ws_size,
                              hipStream_t stream) {
    const float* x     = (const float*)d_in[0];
    const float* Wq    = (const float*)d_in[1];
    const float* bq    = (const float*)d_in[2];
    const float* wr    = (const float*)d_in[3];
    const float* wi    = (const float*)d_in[4];
    const float* gamma = (const float*)d_in[5];
    const float* beta  = (const float*)d_in[6];
    const int*   index = (const int*)d_in[7];
    float* out = (float*)d_out;
    float* ws  = (float*)d_ws;

    const size_t nP     = PPLANE * 8;          // 2M floats (8 MB)
    const size_t nSmall = (size_t)BB * HH * 8; // 32,768 floats (128 KB)

    float *P, *G, *XM, *CF;
    if (ws_size >= (nP + 3 * nSmall) * sizeof(float)) {
        P  = ws;
        G  = P + nP;
        XM = G + nSmall;
        CF = XM + nSmall;
    } else {
        // fall back: P lives in d_out (consumed by kA2 before kD writes out)
        P  = out;
        G  = ws;
        XM = G + nSmall;
        CF = XM + nSmall;
    }

    hipLaunchKernelGGL(kA_dft,     dim3(BB * NSB), dim3(256), 0, stream, x, index, P);
    hipLaunchKernelGGL(kA2_reduce, dim3(BB * HH * 8 / 256), dim3(256), 0, stream, P, G);
    hipLaunchKernelGGL(kB_proj,    dim3(BB * 16), dim3(256), 0, stream, Wq, bq, index, G, XM);
    hipLaunchKernelGGL(kC_modes,   dim3(BB * NH), dim3(512), 0, stream, wr, wi, XM, CF);
    hipLaunchKernelGGL(kD_out,     dim3(BB * (SS / KD_ROWS)), dim3(256), 0, stream, x, CF, gamma, beta, out);
}

// Round 4
// 61.734 us; speedup vs baseline: 1.5858x; 1.1068x over previous
//
#include <hip/hip_runtime.h>
#include <math.h>

#define BB 4
#define SS 4096
#define HH 1024
#define NH 16
#define DK 64
#define NMODES 4
#define NSB 128             // s-chunks for DFT kernel
#define SCHUNK (SS/NSB)     // 32
#define PPLANE ((size_t)BB * NSB * HH)   // one q-plane of P: 512K floats
#define TWO_PI 6.28318530717958647692f

// ---------------- Kernel A: partial 4-mode DFT of x over s ----------------
// Thread owns 4 consecutive channels (float4 loads). P stored as 8 planes:
// P[q*PPLANE + (b*NSB+sb)*HH + c] so each store is wave-contiguous.
__global__ __launch_bounds__(256) void kA_dft(const float* __restrict__ x,
                                              const int* __restrict__ index,
                                              float* __restrict__ P) {
    __shared__ float tab[SCHUNK * 8];
    int t  = threadIdx.x;
    int sb = blockIdx.x & (NSB - 1);
    int b  = blockIdx.x >> 7;

    // fill trig table: 32 rows x 4 modes = 128 entries
    if (t < SCHUNK * NMODES) {
        int sl = t >> 2, m = t & 3;
        int k  = index[m];
        int sv = sb * SCHUNK + sl;
        int r  = (k * sv) & (SS - 1);          // exact phase mod S
        float ang = (float)r * (TWO_PI / (float)SS);
        float sn, cs;
        sincosf(ang, &sn, &cs);
        tab[sl * 8 + m * 2]     = cs;
        tab[sl * 8 + m * 2 + 1] = sn;
    }
    __syncthreads();

    int c0 = t * 4;
    float acc[4][8];
    #pragma unroll
    for (int e = 0; e < 4; ++e)
        #pragma unroll
        for (int q = 0; q < 8; ++q) acc[e][q] = 0.f;

    const float* xp = x + ((size_t)(b * SS + sb * SCHUNK)) * HH + c0;
    #pragma unroll 4
    for (int r = 0; r < SCHUNK; ++r) {
        float4 xv = *(const float4*)(xp + (size_t)r * HH);
        float4 t0 = *(const float4*)&tab[r * 8];      // broadcast (uniform addr)
        float4 t1 = *(const float4*)&tab[r * 8 + 4];
        float xe;
        #pragma unroll
        for (int e = 0; e < 4; ++e) {
            xe = (e == 0) ? xv.x : (e == 1) ? xv.y : (e == 2) ? xv.z : xv.w;
            acc[e][0] += xe * t0.x;  acc[e][1] -= xe * t0.y;  // G = sum x*(cos - i sin)
            acc[e][2] += xe * t0.z;  acc[e][3] -= xe * t0.w;
            acc[e][4] += xe * t1.x;  acc[e][5] -= xe * t1.y;
            acc[e][6] += xe * t1.z;  acc[e][7] -= xe * t1.w;
        }
    }
    size_t base = (size_t)(b * NSB + sb) * HH + c0;
    #pragma unroll
    for (int q = 0; q < 8; ++q) {
        *(float4*)&P[q * PPLANE + base] =
            make_float4(acc[0][q], acc[1][q], acc[2][q], acc[3][q]);
    }
}

// ---------------- Kernel A2: deterministic reduction of partials ----------
// output G in 8 planes per batch: G[(b*8+q)*HH + j]; j fastest -> coalesced
__global__ __launch_bounds__(256) void kA2_reduce(const float* __restrict__ P,
                                                  float* __restrict__ G) {
    int g = blockIdx.x * 256 + threadIdx.x;   // < B*8*H = 32768
    int j = g & (HH - 1);
    int q = (g >> 10) & 7;
    int b = g >> 13;
    const float* pp = P + q * PPLANE + (size_t)b * NSB * HH + j;
    float s = 0.f;
    #pragma unroll 16
    for (int sb = 0; sb < NSB; ++sb)
        s += pp[(size_t)sb * HH];
    G[g] = s;
}

// ---------------- Kernel B: xm[b,c,m] = Wq[c,:] . G[b,:,m] + bias ----------
// 256 blocks: (b, cb) with 16 channels per block; 16-way j-split per channel.
__global__ __launch_bounds__(256) void kB_proj(const float* __restrict__ Wq,
                                               const float* __restrict__ bq,
                                               const int* __restrict__ index,
                                               const float* __restrict__ G,
                                               float* __restrict__ XM) {
    __shared__ float Gs[8 * HH];   // 32 KB, plane layout [q][j]
    int t  = threadIdx.x;
    int cb = blockIdx.x & 63;
    int b  = blockIdx.x >> 6;
    {
        const float4* gsrc = (const float4*)(G + (size_t)b * 8 * HH);
        float4* gdst = (float4*)Gs;
        for (int u = t; u < 2 * HH; u += 256) gdst[u] = gsrc[u];
    }
    __syncthreads();

    int cl = t >> 4, jq = t & 15;
    int c = cb * 16 + cl;
    float acc[8] = {0.f,0.f,0.f,0.f,0.f,0.f,0.f,0.f};
    for (int j0 = jq * 4; j0 < HH; j0 += 64) {
        float4 wv = *(const float4*)&Wq[(size_t)c * HH + j0];
        #pragma unroll
        for (int q = 0; q < 8; ++q) {
            float4 gv = *(const float4*)&Gs[q * HH + j0];
            acc[q] += wv.x * gv.x + wv.y * gv.y + wv.z * gv.z + wv.w * gv.w;
        }
    }
    #pragma unroll
    for (int q = 0; q < 8; ++q) {
        acc[q] += __shfl_xor(acc[q], 1);
        acc[q] += __shfl_xor(acc[q], 2);
        acc[q] += __shfl_xor(acc[q], 4);
        acc[q] += __shfl_xor(acc[q], 8);
    }
    if (jq == 0) {
        float bias = bq[c];
        #pragma unroll
        for (int m = 0; m < NMODES; ++m)
            if (index[m] == 0) acc[2 * m] += bias * (float)SS;  // sum_s e^0 = S
        float* o = XM + ((size_t)(b * HH + c)) * 8;
        *(float4*)o       = make_float4(acc[0], acc[1], acc[2], acc[3]);
        *(float4*)(o + 4) = make_float4(acc[4], acc[5], acc[6], acc[7]);
    }
}

// ---------------- Kernel C: per-head complex mode-mix + irfft coefficients -
#define KC_IQ 8
#define KC_II (DK / KC_IQ)   // 8
__global__ __launch_bounds__(512) void kC_modes(const float* __restrict__ wr,
                                                const float* __restrict__ wi,
                                                const float* __restrict__ XM,
                                                float* __restrict__ CF) {
    __shared__ float xs[DK * 8];             // 2 KB: xm slice for (b,h)
    __shared__ float red[KC_IQ][DK][9];      // padded to 9: conflict-free
    int t = threadIdx.x;
    int o = t & 63, iq = t >> 6;
    int h = blockIdx.x & 15;
    int b = blockIdx.x >> 4;
    for (int u = t; u < DK * 8; u += 512)
        xs[u] = XM[((size_t)(b * HH + h * DK)) * 8 + u];
    __syncthreads();

    float re[4] = {0.f,0.f,0.f,0.f}, im[4] = {0.f,0.f,0.f,0.f};
    #pragma unroll
    for (int ii = 0; ii < KC_II; ++ii) {
        int i = iq * KC_II + ii;
        float4 wrv = *(const float4*)&wr[(((size_t)(h * DK + i)) * DK + o) * 4];
        float4 wiv = *(const float4*)&wi[(((size_t)(h * DK + i)) * DK + o) * 4];
        float xr, xi;
        xr = xs[i * 8 + 0]; xi = xs[i * 8 + 1];
        re[0] += xr * wrv.x - xi * wiv.x;  im[0] += xr * wiv.x + xi * wrv.x;
        xr = xs[i * 8 + 2]; xi = xs[i * 8 + 3];
        re[1] += xr * wrv.y - xi * wiv.y;  im[1] += xr * wiv.y + xi * wrv.y;
        xr = xs[i * 8 + 4]; xi = xs[i * 8 + 5];
        re[2] += xr * wrv.z - xi * wiv.z;  im[2] += xr * wiv.z + xi * wrv.z;
        xr = xs[i * 8 + 6]; xi = xs[i * 8 + 7];
        re[3] += xr * wrv.w - xi * wiv.w;  im[3] += xr * wiv.w + xi * wrv.w;
    }
    #pragma unroll
    for (int m = 0; m < 4; ++m) {
        red[iq][o][2 * m]     = re[m];
        red[iq][o][2 * m + 1] = im[m];
    }
    __syncthreads();
    if (iq == 0) {
        float rr[8];
        #pragma unroll
        for (int q = 0; q < 8; ++q) {
            float s = 0.f;
            #pragma unroll
            for (int g = 0; g < KC_IQ; ++g) s += red[g][o][q];
            rr[q] = s;
        }
        int co = o * NH + h;               // faithful permute(0,3,2,1) flatten
        const float inv = 1.0f / (float)SS;
        float* cp = CF + ((size_t)(b * HH + co)) * 8;
        cp[0] =  rr[0] * inv;              // irfft ignores Im(c0) (pocketfft c2r)
        cp[1] =  2.0f * rr[2] * inv;
        cp[2] = -2.0f * rr[3] * inv;
        cp[3] =  2.0f * rr[4] * inv;
        cp[4] = -2.0f * rr[5] * inv;
        cp[5] =  2.0f * rr[6] * inv;
        cp[6] = -2.0f * rr[7] * inv;
        cp[7] =  0.0f;
    }
}

// ---------------- Kernel D: low-rank irfft + residual + LayerNorm ---------
// 16 rows/block, two 8-row batches; trig in LDS; prefetch x rows; in-place y.
#define KD_ROWS 16
#define KD_RB 8
__global__ __launch_bounds__(256) void kD_out(const float* __restrict__ x,
                                              const float* __restrict__ CF,
                                              const float* __restrict__ gamma,
                                              const float* __restrict__ beta,
                                              float* __restrict__ out) {
    __shared__ float trig[KD_ROWS][2];
    __shared__ float red[4][KD_RB][2];
    int t  = threadIdx.x;
    int b  = blockIdx.x >> 8;
    int s0 = (blockIdx.x & 255) * KD_ROWS;
    int c0 = t * 4;

    if (t < KD_ROWS) {
        float ang = (float)(s0 + t) * (TWO_PI / (float)SS);
        float sn, cs;
        sincosf(ang, &sn, &cs);
        trig[t][0] = cs;
        trig[t][1] = sn;
    }

    const float* cp = CF + (size_t)b * HH * 8 + (size_t)c0 * 8;
    float4 cfa[8];
    #pragma unroll
    for (int e = 0; e < 4; ++e) {
        cfa[2 * e]     = *(const float4*)(cp + e * 8);
        cfa[2 * e + 1] = *(const float4*)(cp + e * 8 + 4);
    }
    float4 g4 = *(const float4*)&gamma[c0];
    float4 b4 = *(const float4*)&beta[c0];
    int w = t >> 6, lane = t & 63;
    __syncthreads();

    for (int batch = 0; batch < KD_ROWS / KD_RB; ++batch) {
        float4 yv[KD_RB];
        #pragma unroll
        for (int r = 0; r < KD_RB; ++r) {
            int s = s0 + batch * KD_RB + r;
            yv[r] = *(const float4*)&x[((size_t)(b * SS + s)) * HH + c0];
        }
        float sm[KD_RB], sq[KD_RB];
        #pragma unroll
        for (int r = 0; r < KD_RB; ++r) {
            int ri = batch * KD_RB + r;
            float c1 = trig[ri][0], s1 = trig[ri][1];
            float c2 = c1 * c1 - s1 * s1, s2 = 2.f * s1 * c1;
            float c3 = c2 * c1 - s2 * s1, s3 = s2 * c1 + c2 * s1;
            float ye[4];
            #pragma unroll
            for (int e = 0; e < 4; ++e) {
                float xe = (e == 0) ? yv[r].x : (e == 1) ? yv[r].y
                         : (e == 2) ? yv[r].z : yv[r].w;
                float4 A = cfa[2 * e], Bv = cfa[2 * e + 1];
                ye[e] = xe + A.x + A.y * c1 + A.z * s1 + A.w * c2
                           + Bv.x * s2 + Bv.y * c3 + Bv.z * s3;
            }
            yv[r] = make_float4(ye[0], ye[1], ye[2], ye[3]);
            sm[r] = ye[0] + ye[1] + ye[2] + ye[3];
            sq[r] = ye[0]*ye[0] + ye[1]*ye[1] + ye[2]*ye[2] + ye[3]*ye[3];
        }
        #pragma unroll
        for (int off = 1; off < 64; off <<= 1) {
            #pragma unroll
            for (int r = 0; r < KD_RB; ++r) {
                sm[r] += __shfl_xor(sm[r], off);
                sq[r] += __shfl_xor(sq[r], off);
            }
        }
        if (lane == 0) {
            #pragma unroll
            for (int r = 0; r < KD_RB; ++r) {
                red[w][r][0] = sm[r];
                red[w][r][1] = sq[r];
            }
        }
        __syncthreads();
        #pragma unroll
        for (int r = 0; r < KD_RB; ++r) {
            int s = s0 + batch * KD_RB + r;
            float tot  = red[0][r][0] + red[1][r][0] + red[2][r][0] + red[3][r][0];
            float totq = red[0][r][1] + red[1][r][1] + red[2][r][1] + red[3][r][1];
            float mean = tot * (1.0f / (float)HH);
            float var  = totq * (1.0f / (float)HH) - mean * mean;
            float rs = rsqrtf(var + 1e-5f);
            float4 o4;
            o4.x = (yv[r].x - mean) * rs * g4.x + b4.x;
            o4.y = (yv[r].y - mean) * rs * g4.y + b4.y;
            o4.z = (yv[r].z - mean) * rs * g4.z + b4.z;
            o4.w = (yv[r].w - mean) * rs * g4.w + b4.w;
            *(float4*)&out[((size_t)(b * SS + s)) * HH + c0] = o4;
        }
        __syncthreads();   // protect red before next batch overwrites
    }
}

extern "C" void kernel_launch(void* const* d_in, const int* in_sizes, int n_in,
                              void* d_out, int out_size, void* d_ws, size_t ws_size,
                              hipStream_t stream) {
    const float* x     = (const float*)d_in[0];
    const float* Wq    = (const float*)d_in[1];
    const float* bq    = (const float*)d_in[2];
    const float* wr    = (const float*)d_in[3];
    const float* wi    = (const float*)d_in[4];
    const float* gamma = (const float*)d_in[5];
    const float* beta  = (const float*)d_in[6];
    const int*   index = (const int*)d_in[7];
    float* out = (float*)d_out;
    float* ws  = (float*)d_ws;

    const size_t nP     = PPLANE * 8;          // 4M floats (16 MB)
    const size_t nSmall = (size_t)BB * HH * 8; // 32,768 floats (128 KB)

    float *P, *G, *XM, *CF;
    if (ws_size >= (nP + 3 * nSmall) * sizeof(float)) {
        P  = ws;
        G  = P + nP;
        XM = G + nSmall;
        CF = XM + nSmall;
    } else {
        // fall back: P lives in d_out (consumed by kA2 before kD writes out)
        P  = out;
        G  = ws;
        XM = G + nSmall;
        CF = XM + nSmall;
    }

    hipLaunchKernelGGL(kA_dft,     dim3(BB * NSB), dim3(256), 0, stream, x, index, P);
    hipLaunchKernelGGL(kA2_reduce, dim3(BB * HH * 8 / 256), dim3(256), 0, stream, P, G);
    hipLaunchKernelGGL(kB_proj,    dim3(BB * 64), dim3(256), 0, stream, Wq, bq, index, G, XM);
    hipLaunchKernelGGL(kC_modes,   dim3(BB * NH), dim3(512), 0, stream, wr, wi, XM, CF);
    hipLaunchKernelGGL(kD_out,     dim3(BB * (SS / KD_ROWS)), dim3(256), 0, stream, x, CF, gamma, beta, out);
}